// Round 11
// baseline (44.740 us; speedup 1.0000x reference)
//
#include <hip/hip_runtime.h>
#include <hip/hip_bf16.h>

// Problem: B=8192, DIM_IN=2048, DIM_OUT=512
//   hazards = relu(x @ W_h^T + b_h)            [8192,512]
//   out     = cumsum(hazards, axis=1) + (x @ W_base^T + b_base)
//
// Round 11: round-7 kernel + NON-TEMPORAL x loads / out stores.
// Theory: all pipelining rounds (3-10) pinned W delivery at ~18 B/cyc/CU ==
// L3 per-CU share -> streaming x evicts the 2MB packed W from each XCD L2,
// so 512 MB of W re-reads hit L3 (the saturated resource). nt on x keeps W
// L2-resident; W then streams at the L2 share (~56 B/cyc/CU).

typedef __attribute__((ext_vector_type(8))) short  short8;
typedef __attribute__((ext_vector_type(4))) short  short4v;
typedef __attribute__((ext_vector_type(4))) float  float4v;
typedef __attribute__((ext_vector_type(4))) float  f32x4;

#define DIN  2048
#define DOUT 512
#define NROW 8192
#define BM   32
#define NPH  (DIN / 64)   // 32 K-phases of 64

static __device__ __forceinline__ unsigned short f2bf(float f) {
  union { float f; unsigned int u; } v; v.f = f;
  unsigned int u = v.u;
  unsigned int r = (u + 0x7FFFu + ((u >> 16) & 1u)) >> 16;   // RNE
  return (unsigned short)r;
}

// barrier WITHOUT the vmcnt(0) drain __syncthreads would emit
static __device__ __forceinline__ void barrier_nd() {
  asm volatile("s_waitcnt lgkmcnt(0)" ::: "memory");
  __builtin_amdgcn_s_barrier();
}

// ---- k_pack: W[512][2048] f32 -> fragment-packed bf16 ---------------------
// fragment (nt, ktp): nt = n>>4 (32), ktp = k>>5 (64).
// lane slot: n = nt*16 + (lane&15), k = ktp*32 + (lane>>4)*8 (+e)
// storage: Wp[ ((nt*64 + ktp)*64 + lane)*8 + e ]  -> wave load = 1KB contig.
__global__ __launch_bounds__(256) void k_pack(const float* __restrict__ W,
                                              unsigned short* __restrict__ Wp) {
  int t    = blockIdx.x * 256 + threadIdx.x;   // 0..131071
  int lane = t & 63;
  int frag = t >> 6;
  int nt   = frag >> 6, ktp = frag & 63;
  int n = nt * 16 + (lane & 15);
  int k = ktp * 32 + (lane >> 4) * 8;
  const float* src = W + (size_t)n * DIN + k;
  float4v a = __builtin_nontemporal_load((const float4v*)src);
  float4v b = __builtin_nontemporal_load((const float4v*)(src + 4));
  unsigned short o[8] = { f2bf(a.x), f2bf(a.y), f2bf(a.z), f2bf(a.w),
                          f2bf(b.x), f2bf(b.y), f2bf(b.z), f2bf(b.w) };
  *(short8*)(Wp + (size_t)t * 8) = *(const short8*)o;
}

// ---- k_main: fused GEMM + bias + relu + row-scan + base -------------------
// grid 256 (BM=32 rows each), 1024 threads = 16 waves; wave w owns cols
// 32w..32w+31 (ni 0..1 -> nt = 2w+ni). acc[mi][ni]: rows mi*16+(lane&15),
// cols ni*16 + (lane>>4)*4 + reg.   (swapped mfma: D[n][m], col slot = m)
__global__ __launch_bounds__(1024, 4) void k_main(
    const float* __restrict__ x, const unsigned short* __restrict__ Wp,
    const float* __restrict__ b_h, const float* __restrict__ w_base,
    const float* __restrict__ b_base, float* __restrict__ out) {
  __shared__ unsigned short Asw[2][BM * 64];   // 2 x 4 KB, XOR-swizzled
  __shared__ float WbL[DIN];                   // 8 KB base-GEMV weights
  __shared__ float stripT[BM][16];             // per-row per-wave strip totals
  __shared__ float baseL[BM];

  const int tid  = threadIdx.x;
  const int lane = tid & 63;
  const int w    = tid >> 6;       // wave 0..15
  const int q    = lane >> 4;      // 0..3
  const int lm   = lane & 15;
  const int m0   = blockIdx.x * BM;
  const bool stager = (tid < 512); // waves 0..7 stage A + base GEMV

  // A staging (tid<512): row sr = tid>>4 (0..31), seg = tid&15 (4 f32)
  const int sr  = tid >> 4;
  const int seg = tid & 15;
  const int sOff = (sr & 31) * 64 + (((seg >> 1) ^ (sr & 7)) << 3) + (seg & 1) * 4;

  for (int i = tid; i < DIN; i += 1024) WbL[i] = w_base[i];

  f32x4 acc[2][2];
  const f32x4 z4 = {0.f, 0.f, 0.f, 0.f};
#pragma unroll
  for (int mi = 0; mi < 2; ++mi)
#pragma unroll
    for (int ni = 0; ni < 2; ++ni) acc[mi][ni] = z4;

  float4v a0, a1;
  short8  wf0[2][2], wf1[2][2];
  float   basePart = 0.f;

  auto loadA = [&](float4v& A, int kt) {
    if (stager)
      A = __builtin_nontemporal_load(
          (const float4v*)(x + (size_t)(m0 + sr) * DIN + kt * 64 + seg * 4));
  };
  auto loadB = [&](short8 wf[2][2], int kt) {
#pragma unroll
    for (int ni = 0; ni < 2; ++ni)
#pragma unroll
      for (int h = 0; h < 2; ++h) {
        int frag = (w * 2 + ni) * 64 + (kt * 2 + h);
        wf[ni][h] = *(const short8*)(Wp + ((size_t)frag << 9) + lane * 8);
      }
  };
  auto writeA = [&](unsigned short* As, const float4v& A, int kt) {
    if (stager) {
      unsigned short t4[4] = { f2bf(A.x), f2bf(A.y), f2bf(A.z), f2bf(A.w) };
      *(short4v*)&As[sOff] = *(const short4v*)t4;
      float4v wb = *(const float4v*)&WbL[kt * 64 + seg * 4];
      basePart += A.x * wb.x + A.y * wb.y + A.z * wb.z + A.w * wb.w;
    }
  };
  auto compute = [&](const unsigned short* As, const short8 wf[2][2]) {
#pragma unroll
    for (int h = 0; h < 2; ++h) {
      short8 xf[2];
#pragma unroll
      for (int mi = 0; mi < 2; ++mi) {
        int r = mi * 16 + lm;
        int g = q + 4 * h;
        xf[mi] = *(const short8*)&As[r * 64 + ((g ^ (r & 7)) << 3)];
      }
#pragma unroll
      for (int mi = 0; mi < 2; ++mi)
#pragma unroll
        for (int ni = 0; ni < 2; ++ni)
          acc[mi][ni] = __builtin_amdgcn_mfma_f32_16x16x32_bf16(
              wf[ni][h], xf[mi], acc[mi][ni], 0, 0, 0);
    }
  };

  // prologue
  loadA(a0, 0); loadB(wf0, 0);
  loadA(a1, 1); loadB(wf1, 1);
  barrier_nd();                    // WbL ready (global prefetches in flight)
  writeA(Asw[0], a0, 0);
  barrier_nd();                    // tile 0 staged

  for (int kt = 0; kt < NPH; kt += 2) {
    // phase A: compute tile kt from buf0 + wf0
    if (kt + 2 < NPH) loadA(a0, kt + 2);
    compute(Asw[0], wf0);
    if (kt + 2 < NPH) loadB(wf0, kt + 2);
    writeA(Asw[1], a1, kt + 1);                  // kt+1 <= 31 always
    barrier_nd();
    // phase B: compute tile kt+1 from buf1 + wf1
    if (kt + 3 < NPH) loadA(a1, kt + 3);
    compute(Asw[1], wf1);
    if (kt + 3 < NPH) loadB(wf1, kt + 3);
    if (kt + 2 < NPH) writeA(Asw[0], a0, kt + 2);
    barrier_nd();
  }

  // ---- base GEMV reduce: 16 consecutive threads share row sr ----
  if (stager) {
    float s = basePart;
    s += __shfl_xor(s, 1); s += __shfl_xor(s, 2);
    s += __shfl_xor(s, 4); s += __shfl_xor(s, 8);
    if (seg == 0) baseL[sr] = s + b_base[0];
  }

  // ---- epilogue: bias + relu + scan over this wave's 32-col strip ----
  float runp[2][2][4];   // inclusive in-run (4-col) prefix
  float Eq[2][2];        // sum of runs with smaller q (same 16-col group)
  float niPre[2][2];     // sum of full 16-col groups with smaller ni
  float Tst[2];          // strip total per row
#pragma unroll
  for (int mi = 0; mi < 2; ++mi) {
    float run = 0.f;
#pragma unroll
    for (int ni = 0; ni < 2; ++ni) {
      float4v b4 = *(const float4v*)(b_h + w * 32 + ni * 16 + q * 4);
      f32x4 v = acc[mi][ni];
      float h0 = fmaxf(v.x + b4.x, 0.f);
      float h1 = fmaxf(v.y + b4.y, 0.f);
      float h2 = fmaxf(v.z + b4.z, 0.f);
      float h3 = fmaxf(v.w + b4.w, 0.f);
      runp[mi][ni][0] = h0;
      runp[mi][ni][1] = h0 + h1;
      runp[mi][ni][2] = h0 + h1 + h2;
      runp[mi][ni][3] = h0 + h1 + h2 + h3;
      float S = runp[mi][ni][3];
      float u1 = __shfl_up(S, 16);
      float u2 = __shfl_up(S, 32);
      float u3 = __shfl_up(S, 48);
      Eq[mi][ni] = (q >= 1 ? u1 : 0.f) + (q >= 2 ? u2 : 0.f) + (q >= 3 ? u3 : 0.f);
      float G = S + __shfl_xor(S, 16);
      G += __shfl_xor(G, 32);
      niPre[mi][ni] = run;
      run += G;
    }
    Tst[mi] = run;
  }
  if (q == 0) {
#pragma unroll
    for (int mi = 0; mi < 2; ++mi) stripT[mi * 16 + lm][w] = Tst[mi];
  }
  barrier_nd();

#pragma unroll
  for (int mi = 0; mi < 2; ++mi) {
    const int row = mi * 16 + lm;
    float c = baseL[row];
#pragma unroll
    for (int j4 = 0; j4 < 4; ++j4) {
      float4v s = *(const float4v*)&stripT[row][j4 * 4];
      c += (w > j4 * 4 + 0 ? s.x : 0.f) + (w > j4 * 4 + 1 ? s.y : 0.f) +
           (w > j4 * 4 + 2 ? s.z : 0.f) + (w > j4 * 4 + 3 ? s.w : 0.f);
    }
#pragma unroll
    for (int ni = 0; ni < 2; ++ni) {
      float base = c + niPre[mi][ni] + Eq[mi][ni];
      float4v o = { runp[mi][ni][0] + base, runp[mi][ni][1] + base,
                    runp[mi][ni][2] + base, runp[mi][ni][3] + base };
      __builtin_nontemporal_store(
          o, (float4v*)(out + (size_t)(m0 + row) * DOUT + w * 32 + ni * 16 + q * 4));
    }
  }
}

// ---------------------------------------------------------------------------
extern "C" void kernel_launch(void* const* d_in, const int* in_sizes, int n_in,
                              void* d_out, int out_size, void* d_ws, size_t ws_size,
                              hipStream_t stream) {
  const float* x   = (const float*)d_in[0];  // [8192,2048]
  const float* Wh  = (const float*)d_in[1];  // [512,2048]
  const float* bh  = (const float*)d_in[2];  // [512]
  const float* Wb0 = (const float*)d_in[3];  // [1,2048]
  const float* bb  = (const float*)d_in[4];  // [1]
  float* out = (float*)d_out;

  unsigned short* Wp = (unsigned short*)d_ws;   // 2 MiB fragment-packed W

  k_pack<<<dim3((DOUT * DIN) / (256 * 8)), dim3(256), 0, stream>>>(Wh, Wp);
  k_main<<<dim3(NROW / BM), dim3(1024), 0, stream>>>(x, Wp, bh, Wb0, bb, out);
}